// Round 2
// baseline (502.625 us; speedup 1.0000x reference)
//
#include <hip/hip_runtime.h>
#include <hip/hip_fp16.h>

#define NSNAP 8192
#define PER 32
#define SLOPE 0.01f

using half8   = __attribute__((ext_vector_type(8))) _Float16;
using floatx4 = __attribute__((ext_vector_type(4))) float;

__device__ __forceinline__ float leaky(float x) { return x >= 0.f ? x : SLOPE * x; }

__device__ __forceinline__ unsigned pack2(float a, float b) {
    __half2 h = __floats2half2_rn(a, b);
    return *reinterpret_cast<unsigned*>(&h);
}

// Pack W f32[256][256] into f16 MFMA B-fragment order, 3 matrices:
// Wh[mat][(k0*16 + w*4 + j)*64 + lane] (half8) = W[n = w*64+j*16+(lane&15)]
//                                                 [k = k0*32+(lane>>4)*8 .. +8]
// 8192 half8 per matrix -> 32 blocks x 256 threads per matrix, grid = 96.
__global__ __launch_bounds__(256) void pack_w3(const float* __restrict__ W0,
                                               const float* __restrict__ W1,
                                               const float* __restrict__ W2,
                                               _Float16* __restrict__ Wh) {
    const int mat = blockIdx.x >> 5;
    const float* W = mat == 0 ? W0 : (mat == 1 ? W1 : W2);
    const int t = (blockIdx.x & 31) * 256 + threadIdx.x;  // 0..8191
    const int lane = t & 63;
    const int wj = (t >> 6) & 15;
    const int k0 = t >> 10;  // 0..7
    const int n = (wj >> 2) * 64 + (wj & 3) * 16 + (lane & 15);
    const int k = k0 * 32 + (lane >> 4) * 8;
    const float4 v0 = *(const float4*)(W + (long)n * 256 + k);
    const float4 v1 = *(const float4*)(W + (long)n * 256 + k + 4);
    *(uint4*)(Wh + (long)mat * 65536 + (long)t * 8) =
        make_uint4(pack2(v0.x, v0.y), pack2(v0.z, v0.w), pack2(v1.x, v1.y), pack2(v1.z, v1.w));
}

// One kernel does EVERYTHING for 2 snapshots (64 edges) per block; wave w = head w.
//  1) gather 64 paper rows -> LDS (fragment-swizzled)
//  2) F rows (2x256) = snapshots[2 rows] @ W_dst^T via 2-row MFMA (overlaps staging)
//  3) main gather-GEMM (feat_src) from LDS + L2-resident packed W_src
//  4) attention logits + segment softmax + weighted aggregate -> SO (2x256, LDS)
//  5) out rows (2x256) = SO @ W_out^T via 2-row MFMA -> global f32
__global__ __launch_bounds__(256, 2) void fused_all(
    const float* __restrict__ papers, const float* __restrict__ snapshots,
    const _Float16* __restrict__ Whs, const _Float16* __restrict__ Whd,
    const _Float16* __restrict__ Who, const float* __restrict__ b_src,
    const float* __restrict__ b_dst, const float* __restrict__ b_out,
    const float* __restrict__ emb_cite, const float* __restrict__ emb_ref,
    const float* __restrict__ emb_target, const float* __restrict__ snap_emb,
    const float* __restrict__ attn, const float* __restrict__ attn_t,
    const int* __restrict__ types, const int* __restrict__ is_cite,
    const int* __restrict__ sel, float* __restrict__ out) {
    __shared__ _Float16 Asl[64 * 256];  // fragment-swizzled A-tile, 32 KB
    __shared__ _Float16 SOsl[2 * 256];  // aggregated SO rows, f16, 1 KB
    __shared__ int ic_l[64];

    const int tid = threadIdx.x;
    const int lane = tid & 63;
    const int wave = tid >> 6;
    const int l15 = lane & 15;
    const int quad = lane >> 4;
    const int sbase = blockIdx.x * 2;
    const int ebase = blockIdx.x * 64;

    if (tid < 64) ic_l[tid] = is_cite[sel[ebase + tid]];

    // ---- 1) stage gathered A-tile: wave w owns rows w*16+l15, 4 lanes/row ----
    {
        const int row = wave * 16 + l15;  // 0..63
        const long arow = (long)sel[ebase + row];
        const float* src = papers + arow * 256;
#pragma unroll
        for (int m = 0; m < 16; m++) {
            // lanes quad=0..3 of a row cover floats [m*16, m*16+16) = one 64B line
            const float4 v = *(const float4*)(src + m * 16 + quad * 4);
            const int c8 = m * 2 + (quad >> 1);  // 8-float chunk index 0..31
            const int slot = (c8 >> 2) * 256 + wave * 64 + (c8 & 3) * 16 + l15;
            *(uint2*)(&Asl[slot * 8 + (quad & 1) * 4]) =
                make_uint2(pack2(v.x, v.y), pack2(v.z, v.w));
        }
    }

    // ---- 2) F rows: 2-row MFMA gemm (independent of Asl; hides staging latency) ----
    // A-frag: lane holds row l15 (only rows 0-1 real; others read row l15&1, ignored),
    //         k = k0*32 + quad*8 .. +8
    float F0_j[4], F1_j[4];
    {
        floatx4 accf[4];
#pragma unroll
        for (int j = 0; j < 4; j++) accf[j] = (floatx4)0.f;
        const float* srow = snapshots + (long)(sbase + (l15 & 1)) * 256;
        for (int k0 = 0; k0 < 8; k0++) {
            const float4 s0 = *(const float4*)(srow + k0 * 32 + quad * 8);
            const float4 s1 = *(const float4*)(srow + k0 * 32 + quad * 8 + 4);
            uint4 u = make_uint4(pack2(s0.x, s0.y), pack2(s0.z, s0.w),
                                 pack2(s1.x, s1.y), pack2(s1.z, s1.w));
            const half8 af = *reinterpret_cast<half8*>(&u);
#pragma unroll
            for (int j = 0; j < 4; j++) {
                const half8 bf =
                    *reinterpret_cast<const half8*>(Whd + ((k0 * 16 + wave * 4 + j) * 64 + lane) * 8);
                accf[j] = __builtin_amdgcn_mfma_f32_16x16x32_f16(af, bf, accf[j], 0, 0, 0);
            }
        }
        // C layout: row = quad*4 + r, col = 64*wave + j*16 + l15.
        // Row 0 -> lane(quad=0,l15), reg 0; row 1 -> reg 1. Broadcast from lane l15.
#pragma unroll
        for (int j = 0; j < 4; j++) {
            const float bd = b_dst[64 * wave + j * 16 + l15];
            F0_j[j] = __shfl(accf[j][0], l15) + bd;
            F1_j[j] = __shfl(accf[j][1], l15) + bd;
        }
    }
    __syncthreads();

    floatx4 acc[4][4];
#pragma unroll
    for (int i = 0; i < 4; i++)
#pragma unroll
        for (int j = 0; j < 4; j++) acc[i][j] = (floatx4)0.f;

    // ---- 3) barrier-free K-loop: LDS A-frags + global (L2) W-frags + MFMA ----
    for (int k0 = 0; k0 < 8; k0++) {
        half8 af[4], bf[4];
#pragma unroll
        for (int i = 0; i < 4; i++)
            af[i] = *reinterpret_cast<const half8*>(&Asl[(k0 * 256 + i * 64 + lane) * 8]);
#pragma unroll
        for (int j = 0; j < 4; j++)
            bf[j] = *reinterpret_cast<const half8*>(Whs + ((k0 * 16 + wave * 4 + j) * 64 + lane) * 8);
#pragma unroll
        for (int i = 0; i < 4; i++)
#pragma unroll
            for (int j = 0; j < 4; j++)
                acc[i][j] = __builtin_amdgcn_mfma_f32_16x16x32_f16(af[i], bf[j], acc[i][j], 0, 0, 0);
    }

    // ===== 4) fused attention epilogue =====
    // acc[i][j][r] = feat[row = i*16 + quad*4 + r][col = 64*wave + j*16 + l15]
    float bsrc_j[4], attn_j[4];
#pragma unroll
    for (int j = 0; j < 4; j++) {
        const int col = 64 * wave + j * 16 + l15;
        bsrc_j[j] = b_src[col];
        attn_j[j] = attn[col];
    }
#pragma unroll
    for (int i = 0; i < 4; i++)
#pragma unroll
        for (int j = 0; j < 4; j++)
#pragma unroll
            for (int r = 0; r < 4; r++) acc[i][j][r] += bsrc_j[j];

    // et[sn][ic] for this head: 64-dim reduce across the wave
    const int D = 64 * wave + lane;
    const float at_d = attn_t[D];
    const float src0 = emb_cite[D] + emb_ref[D] + emb_target[D];
    const float src1 = emb_cite[256 + D] + emb_ref[256 + D] + emb_target[256 + D];
    float et[2][2];
#pragma unroll
    for (int sn = 0; sn < 2; sn++) {
        const float dstt = snap_emb[types[sbase + sn] * 256 + D];
        float p0 = leaky(src0 + dstt) * at_d;
        float p1 = leaky(src1 + dstt) * at_d;
#pragma unroll
        for (int off = 32; off; off >>= 1) {
            p0 += __shfl_xor(p0, off);
            p1 += __shfl_xor(p1, off);
        }
        et[sn][0] = p0;
        et[sn][1] = p1;
    }

    // logits: in-lane over j + shfl over the 16 l15 lanes
    float lg[4][4];
#pragma unroll
    for (int i = 0; i < 4; i++) {
        const int sn = i >> 1;
#pragma unroll
        for (int r = 0; r < 4; r++) {
            float p = 0.f;
#pragma unroll
            for (int j = 0; j < 4; j++)
                p += leaky(acc[i][j][r] + (sn == 0 ? F0_j[j] : F1_j[j])) * attn_j[j];
#pragma unroll
            for (int off = 1; off <= 8; off <<= 1) p += __shfl_xor(p, off);
            const int row = i * 16 + quad * 4 + r;
            lg[i][r] = p + et[sn][ic_l[row]];
        }
    }

    // segment softmax over 32 edges per snapshot
    float aw[4][4];
#pragma unroll
    for (int sn = 0; sn < 2; sn++) {
        float m = -3.4e38f;
#pragma unroll
        for (int ii = 0; ii < 2; ii++)
#pragma unroll
            for (int r = 0; r < 4; r++) m = fmaxf(m, lg[sn * 2 + ii][r]);
        m = fmaxf(m, __shfl_xor(m, 16));
        m = fmaxf(m, __shfl_xor(m, 32));
        float den = 0.f;
#pragma unroll
        for (int ii = 0; ii < 2; ii++)
#pragma unroll
            for (int r = 0; r < 4; r++) {
                const float ex = __expf(lg[sn * 2 + ii][r] - m);
                aw[sn * 2 + ii][r] = ex;
                den += ex;
            }
        den += __shfl_xor(den, 16);
        den += __shfl_xor(den, 32);
        const float inv = 1.f / den;
#pragma unroll
        for (int ii = 0; ii < 2; ii++)
#pragma unroll
            for (int r = 0; r < 4; r++) aw[sn * 2 + ii][r] *= inv;
    }

    // weighted aggregate -> SO rows in LDS (f16)
#pragma unroll
    for (int sn = 0; sn < 2; sn++) {
#pragma unroll
        for (int j = 0; j < 4; j++) {
            float o = 0.f;
#pragma unroll
            for (int ii = 0; ii < 2; ii++)
#pragma unroll
                for (int r = 0; r < 4; r++) o += aw[sn * 2 + ii][r] * acc[sn * 2 + ii][j][r];
            o += __shfl_xor(o, 16);
            o += __shfl_xor(o, 32);
            if (quad == sn) SOsl[sn * 256 + 64 * wave + j * 16 + l15] = (_Float16)o;
        }
    }
    __syncthreads();

    // ---- 5) out rows: 2-row MFMA gemm from SOsl ----
    {
        floatx4 acco[4];
#pragma unroll
        for (int j = 0; j < 4; j++) acco[j] = (floatx4)0.f;
        for (int k0 = 0; k0 < 8; k0++) {
            // A-frag row l15 (rows 0-1 real; others alias row l15&1), 16B LDS read,
            // same-address across 8 lanes -> broadcast, conflict-free
            const half8 af =
                *reinterpret_cast<const half8*>(&SOsl[(l15 & 1) * 256 + k0 * 32 + quad * 8]);
#pragma unroll
            for (int j = 0; j < 4; j++) {
                const half8 bf =
                    *reinterpret_cast<const half8*>(Who + ((k0 * 16 + wave * 4 + j) * 64 + lane) * 8);
                acco[j] = __builtin_amdgcn_mfma_f32_16x16x32_f16(af, bf, acco[j], 0, 0, 0);
            }
        }
        if (quad == 0) {
#pragma unroll
            for (int j = 0; j < 4; j++) {
                const int col = 64 * wave + j * 16 + l15;
                const float bo = b_out[col];
                out[(long)sbase * 256 + col] = acco[j][0] + bo;
                out[(long)(sbase + 1) * 256 + col] = acco[j][1] + bo;
            }
        }
    }
}

extern "C" void kernel_launch(void* const* d_in, const int* in_sizes, int n_in,
                              void* d_out, int out_size, void* d_ws, size_t ws_size,
                              hipStream_t stream) {
    const float* papers     = (const float*)d_in[0];
    const float* snapshots  = (const float*)d_in[1];
    const float* W_src      = (const float*)d_in[2];
    const float* b_src      = (const float*)d_in[3];
    const float* W_dst      = (const float*)d_in[4];
    const float* b_dst      = (const float*)d_in[5];
    const float* W_out      = (const float*)d_in[6];
    const float* b_out      = (const float*)d_in[7];
    const float* emb_cite   = (const float*)d_in[8];
    const float* emb_ref    = (const float*)d_in[9];
    const float* emb_target = (const float*)d_in[10];
    const float* snap_emb   = (const float*)d_in[11];
    const float* attn       = (const float*)d_in[12];
    const float* attn_t     = (const float*)d_in[13];
    const int* types        = (const int*)d_in[14];
    const int* is_cite      = (const int*)d_in[15];
    const int* sel          = (const int*)d_in[16];  // int32 (harness convention)

    _Float16* Wh = (_Float16*)d_ws;  // 3 x 131,072 B (W_src, W_dst, W_out fragment order)
    _Float16* Whs = Wh;
    _Float16* Whd = Wh + 65536;
    _Float16* Who = Wh + 131072;

    // 1) pre-pack all three weight matrices into MFMA fragment order
    pack_w3<<<96, 256, 0, stream>>>(W_src, W_dst, W_out, Wh);
    // 2) everything else in one kernel
    fused_all<<<NSNAP / 2, 256, 0, stream>>>(papers, snapshots, Whs, Whd, Who, b_src, b_dst,
                                             b_out, emb_cite, emb_ref, emb_target, snap_emb,
                                             attn, attn_t, types, is_cite, sel, (float*)d_out);
}

// Round 3
// 382.884 us; speedup vs baseline: 1.3127x; 1.3127x over previous
//
#include <hip/hip_runtime.h>
#include <hip/hip_fp16.h>
#include <type_traits>

#define NSNAP 8192
#define PER 32
#define SLOPE 0.01f

using half8   = __attribute__((ext_vector_type(8))) _Float16;
using floatx4 = __attribute__((ext_vector_type(4))) float;

__device__ __forceinline__ float leaky(float x) { return x >= 0.f ? x : SLOPE * x; }

__device__ __forceinline__ unsigned pack2(float a, float b) {
    __half2 h = __floats2half2_rn(a, b);
    return *reinterpret_cast<unsigned*>(&h);
}

// C[M,256] = A[M,256] @ W[256,256]^T + bias, 64x64 tiles, grid (M/64, 4[+1]).
// DO_PACK folds the W_src->MFMA-fragment pack into blockIdx.y==4 (first 32 blocks).
template <typename AT, typename OT, bool DO_PACK>
__global__ __launch_bounds__(256) void gemm64(const AT* __restrict__ A,
                                              const float* __restrict__ W,
                                              const float* __restrict__ bias,
                                              OT* __restrict__ Cout, int M,
                                              const float* __restrict__ Wsrc,
                                              _Float16* __restrict__ Wh) {
    if constexpr (DO_PACK) {
        if (blockIdx.y == 4) {
            // Pre-pack W_src f32[256][256] into f16 MFMA B-fragment order:
            // Wh[(k0*16 + w*4 + j)*64 + lane] (half8) = W[n = w*64+j*16+(lane&15)]
            //                                            [k = k0*32+(lane>>4)*8 ..+8]
            if (blockIdx.x < 32) {
                const int t = blockIdx.x * 256 + threadIdx.x;  // 0..8191
                const int lane = t & 63;
                const int wj = (t >> 6) & 15;
                const int k0 = t >> 10;  // 0..7
                const int n = (wj >> 2) * 64 + (wj & 3) * 16 + (lane & 15);
                const int k = k0 * 32 + (lane >> 4) * 8;
                const float4 v0 = *(const float4*)(Wsrc + (long)n * 256 + k);
                const float4 v1 = *(const float4*)(Wsrc + (long)n * 256 + k + 4);
                *(uint4*)(Wh + (long)t * 8) = make_uint4(pack2(v0.x, v0.y), pack2(v0.z, v0.w),
                                                         pack2(v1.x, v1.y), pack2(v1.z, v1.w));
            }
            return;
        }
    }
    constexpr int LDA = 40;
    __shared__ _Float16 Asl[64 * LDA];
    __shared__ _Float16 Wsl[64 * LDA];

    const int m0 = blockIdx.x * 64;
    const int n0 = blockIdx.y * 64;
    const int tid = threadIdx.x;
    const int lane = tid & 63;
    const int wave = tid >> 6;
    const int wm = (wave & 1) * 32;
    const int wn = (wave >> 1) * 32;
    const int l15 = lane & 15;
    const int quad = lane >> 4;

    floatx4 acc[2][2];
#pragma unroll
    for (int i = 0; i < 2; i++)
#pragma unroll
        for (int j = 0; j < 2; j++) acc[i][j] = (floatx4)0.f;

    for (int k0 = 0; k0 < 256; k0 += 32) {
        __syncthreads();
#pragma unroll
        for (int it = 0; it < 2; ++it) {
            const int idx = tid + it * 256;  // 512 slots: 64 rows x 8 float4-chunks
            const int row = idx >> 3;
            const int c4 = idx & 7;
            if constexpr (std::is_same_v<AT, float>) {
                const float4 v = *(const float4*)(A + (long)(m0 + row) * 256 + k0 + c4 * 4);
                *(uint2*)(&Asl[row * LDA + c4 * 4]) = make_uint2(pack2(v.x, v.y), pack2(v.z, v.w));
            } else {
                const uint2 v = *(const uint2*)(A + (long)(m0 + row) * 256 + k0 + c4 * 4);
                *(uint2*)(&Asl[row * LDA + c4 * 4]) = v;
            }
            const float4 w = *(const float4*)(W + (long)(n0 + row) * 256 + k0 + c4 * 4);
            *(uint2*)(&Wsl[row * LDA + c4 * 4]) = make_uint2(pack2(w.x, w.y), pack2(w.z, w.w));
        }
        __syncthreads();

        half8 af[2], bf[2];
#pragma unroll
        for (int i = 0; i < 2; i++)
            af[i] = *reinterpret_cast<const half8*>(&Asl[(wm + i * 16 + l15) * LDA + quad * 8]);
#pragma unroll
        for (int j = 0; j < 2; j++)
            bf[j] = *reinterpret_cast<const half8*>(&Wsl[(wn + j * 16 + l15) * LDA + quad * 8]);
#pragma unroll
        for (int i = 0; i < 2; i++)
#pragma unroll
            for (int j = 0; j < 2; j++)
                acc[i][j] = __builtin_amdgcn_mfma_f32_16x16x32_f16(af[i], bf[j], acc[i][j], 0, 0, 0);
    }

#pragma unroll
    for (int j = 0; j < 2; j++) {
        const int gcol = n0 + wn + j * 16 + l15;
        const float bv = bias[gcol];
#pragma unroll
        for (int i = 0; i < 2; i++) {
            const int rbase = m0 + wm + i * 16 + quad * 4;
#pragma unroll
            for (int r = 0; r < 4; r++) {
                const float v = acc[i][j][r] + bv;
                if constexpr (std::is_same_v<OT, __half>)
                    Cout[(long)(rbase + r) * 256 + gcol] = __float2half(v);
                else
                    Cout[(long)(rbase + r) * 256 + gcol] = v;
            }
        }
    }
}

// Fused gather-GEMM + attention. Block = 2 snapshots (64 edges); wave w = head w.
// A-tile (64x256) gathered+converted to LDS once (fragment-swizzled); W fragments
// loaded straight from L2-resident pre-packed Wh. Single barrier, barrier-free K-loop.
// Occupancy v3: LDS = 33.3 KB -> 4 blocks/CU fit (133 KB < 160 KB); the gather is
// HBM-latency-bound, so resident-wave count is the throughput lever.
__global__ __launch_bounds__(256, 4) void fused_attn(
    const float* __restrict__ papers, const _Float16* __restrict__ Wh,
    const float* __restrict__ b_src, const float* __restrict__ F,
    const float* __restrict__ emb_cite, const float* __restrict__ emb_ref,
    const float* __restrict__ emb_target, const float* __restrict__ snap_emb,
    const float* __restrict__ attn, const float* __restrict__ attn_t,
    const int* __restrict__ types, const int* __restrict__ is_cite,
    const int* __restrict__ sel, __half* __restrict__ SO) {
    __shared__ _Float16 Asl[64 * 256];  // fragment-swizzled, 32 KB
    __shared__ int ic_l[64];

    const int tid = threadIdx.x;
    const int lane = tid & 63;
    const int wave = tid >> 6;
    const int l15 = lane & 15;
    const int quad = lane >> 4;
    const int sbase = blockIdx.x * 2;
    const int ebase = blockIdx.x * 64;

    if (tid < 64) ic_l[tid] = is_cite[sel[ebase + tid]];

    // ---- stage whole gathered A-tile: wave w owns rows w*16+l15, 4 lanes/row ----
    {
        const int row = wave * 16 + l15;              // 0..63
        const long arow = (long)sel[ebase + row];
        const float* src = papers + arow * 256;
#pragma unroll
        for (int m = 0; m < 16; m++) {
            // lanes quad=0..3 of a row cover floats [m*16, m*16+16) = one 64B line
            const float4 v = *(const float4*)(src + m * 16 + quad * 4);
            const int c8 = m * 2 + (quad >> 1);       // 8-float chunk index 0..31
            const int slot = (c8 >> 2) * 256 + wave * 64 + (c8 & 3) * 16 + l15;
            *(uint2*)(&Asl[slot * 8 + (quad & 1) * 4]) =
                make_uint2(pack2(v.x, v.y), pack2(v.z, v.w));
        }
    }
    __syncthreads();  // the only barrier

    floatx4 acc[4][4];
#pragma unroll
    for (int i = 0; i < 4; i++)
#pragma unroll
        for (int j = 0; j < 4; j++) acc[i][j] = (floatx4)0.f;

    // ---- barrier-free K-loop: LDS A-frags + global (L2) W-frags + MFMA ----
    for (int k0 = 0; k0 < 8; k0++) {
        half8 af[4], bf[4];
#pragma unroll
        for (int i = 0; i < 4; i++)
            af[i] = *reinterpret_cast<const half8*>(&Asl[(k0 * 256 + i * 64 + lane) * 8]);
#pragma unroll
        for (int j = 0; j < 4; j++)
            bf[j] = *reinterpret_cast<const half8*>(Wh + ((k0 * 16 + wave * 4 + j) * 64 + lane) * 8);
#pragma unroll
        for (int i = 0; i < 4; i++)
#pragma unroll
            for (int j = 0; j < 4; j++)
                acc[i][j] = __builtin_amdgcn_mfma_f32_16x16x32_f16(af[i], bf[j], acc[i][j], 0, 0, 0);
    }

    // ===== fused epilogue =====
    // acc[i][j][r] = feat[row = i*16 + quad*4 + r][col = 64*wave + j*16 + l15]
    float bsrc_j[4], attn_j[4], F0_j[4], F1_j[4];
#pragma unroll
    for (int j = 0; j < 4; j++) {
        const int col = 64 * wave + j * 16 + l15;
        bsrc_j[j] = b_src[col];
        attn_j[j] = attn[col];
        F0_j[j] = F[(long)sbase * 256 + col];
        F1_j[j] = F[(long)(sbase + 1) * 256 + col];
    }
#pragma unroll
    for (int i = 0; i < 4; i++)
#pragma unroll
        for (int j = 0; j < 4; j++)
#pragma unroll
            for (int r = 0; r < 4; r++) acc[i][j][r] += bsrc_j[j];

    // et[sn][ic] for this head: 64-dim reduce across the wave
    const int D = 64 * wave + lane;
    const float at_d = attn_t[D];
    const float src0 = emb_cite[D] + emb_ref[D] + emb_target[D];
    const float src1 = emb_cite[256 + D] + emb_ref[256 + D] + emb_target[256 + D];
    float et[2][2];
#pragma unroll
    for (int sn = 0; sn < 2; sn++) {
        const float dstt = snap_emb[types[sbase + sn] * 256 + D];
        float p0 = leaky(src0 + dstt) * at_d;
        float p1 = leaky(src1 + dstt) * at_d;
#pragma unroll
        for (int off = 32; off; off >>= 1) {
            p0 += __shfl_xor(p0, off);
            p1 += __shfl_xor(p1, off);
        }
        et[sn][0] = p0;
        et[sn][1] = p1;
    }

    // logits: in-lane over j + shfl over the 16 l15 lanes
    float lg[4][4];
#pragma unroll
    for (int i = 0; i < 4; i++) {
        const int sn = i >> 1;
#pragma unroll
        for (int r = 0; r < 4; r++) {
            float p = 0.f;
#pragma unroll
            for (int j = 0; j < 4; j++)
                p += leaky(acc[i][j][r] + (sn == 0 ? F0_j[j] : F1_j[j])) * attn_j[j];
#pragma unroll
            for (int off = 1; off <= 8; off <<= 1) p += __shfl_xor(p, off);
            const int row = i * 16 + quad * 4 + r;
            lg[i][r] = p + et[sn][ic_l[row]];
        }
    }

    // segment softmax over 32 edges per snapshot
    float aw[4][4];
#pragma unroll
    for (int sn = 0; sn < 2; sn++) {
        float m = -3.4e38f;
#pragma unroll
        for (int ii = 0; ii < 2; ii++)
#pragma unroll
            for (int r = 0; r < 4; r++) m = fmaxf(m, lg[sn * 2 + ii][r]);
        m = fmaxf(m, __shfl_xor(m, 16));
        m = fmaxf(m, __shfl_xor(m, 32));
        float den = 0.f;
#pragma unroll
        for (int ii = 0; ii < 2; ii++)
#pragma unroll
            for (int r = 0; r < 4; r++) {
                const float ex = __expf(lg[sn * 2 + ii][r] - m);
                aw[sn * 2 + ii][r] = ex;
                den += ex;
            }
        den += __shfl_xor(den, 16);
        den += __shfl_xor(den, 32);
        const float inv = 1.f / den;
#pragma unroll
        for (int ii = 0; ii < 2; ii++)
#pragma unroll
            for (int r = 0; r < 4; r++) aw[sn * 2 + ii][r] *= inv;
    }

    // weighted aggregate; write SO (f16)
#pragma unroll
    for (int sn = 0; sn < 2; sn++) {
#pragma unroll
        for (int j = 0; j < 4; j++) {
            float o = 0.f;
#pragma unroll
            for (int ii = 0; ii < 2; ii++)
#pragma unroll
                for (int r = 0; r < 4; r++) o += aw[sn * 2 + ii][r] * acc[sn * 2 + ii][j][r];
            o += __shfl_xor(o, 16);
            o += __shfl_xor(o, 32);
            if (quad == sn)
                SO[(long)(sbase + sn) * 256 + 64 * wave + j * 16 + l15] = __float2half(o);
        }
    }
}

extern "C" void kernel_launch(void* const* d_in, const int* in_sizes, int n_in,
                              void* d_out, int out_size, void* d_ws, size_t ws_size,
                              hipStream_t stream) {
    const float* papers     = (const float*)d_in[0];
    const float* snapshots  = (const float*)d_in[1];
    const float* W_src      = (const float*)d_in[2];
    const float* b_src      = (const float*)d_in[3];
    const float* W_dst      = (const float*)d_in[4];
    const float* b_dst      = (const float*)d_in[5];
    const float* W_out      = (const float*)d_in[6];
    const float* b_out      = (const float*)d_in[7];
    const float* emb_cite   = (const float*)d_in[8];
    const float* emb_ref    = (const float*)d_in[9];
    const float* emb_target = (const float*)d_in[10];
    const float* snap_emb   = (const float*)d_in[11];
    const float* attn       = (const float*)d_in[12];
    const float* attn_t     = (const float*)d_in[13];
    const int* types        = (const int*)d_in[14];
    const int* is_cite      = (const int*)d_in[15];
    const int* sel          = (const int*)d_in[16];  // int32 (harness convention)

    char* ws = (char*)d_ws;
    float*     F    = (float*)ws;                     // 8,388,608 B
    __half*    SO   = (__half*)(ws + 8388608);        // 4,194,304 B
    _Float16*  Wh   = (_Float16*)(ws + 12582912);     //   131,072 B (fragment order)

    // 1) F = snapshots @ W_dst.T + b_dst (fp32), + fold in W_src fragment pack
    gemm64<float, float, true><<<dim3(128, 5), 256, 0, stream>>>(snapshots, W_dst, b_dst, F,
                                                                 NSNAP, W_src, Wh);
    // 2) fused gather-GEMM + attention + softmax + aggregate -> SO
    fused_attn<<<NSNAP / 2, 256, 0, stream>>>(papers, Wh, b_src, F, emb_cite, emb_ref,
                                              emb_target, snap_emb, attn, attn_t, types,
                                              is_cite, sel, SO);
    // 3) out = SO @ W_out.T + b_out (fp32)
    gemm64<__half, float, false><<<dim3(128, 4), 256, 0, stream>>>(SO, W_out, b_out,
                                                                   (float*)d_out, NSNAP,
                                                                   nullptr, nullptr);
}